// Round 8
// baseline (1816.706 us; speedup 1.0000x reference)
//
#include <hip/hip_runtime.h>
#include <hip/hip_bf16.h>

typedef __bf16 bf16x8 __attribute__((ext_vector_type(8)));
typedef float  f32x4  __attribute__((ext_vector_type(4)));
typedef short  s16x4  __attribute__((ext_vector_type(4)));
typedef unsigned short u16;

#define L2E 1.44269504088896f
#define SBAR  __builtin_amdgcn_s_barrier()
#define SCHED __builtin_amdgcn_sched_barrier(0)
#define VSZ 25165824  // 32768*768, one att/view slice

static __device__ __forceinline__ u16 f2bf(float f) {
  unsigned u = __builtin_bit_cast(unsigned, f);
  u += 0x7fffu + ((u >> 16) & 1u);
  return (u16)(u >> 16);
}

static __device__ __forceinline__ void gld_lds16(const void* g, void* l) {
  __builtin_amdgcn_global_load_lds((const __attribute__((address_space(1))) unsigned*)g,
                                   (__attribute__((address_space(3))) unsigned*)l, 16, 0, 0);
}

// ---------------------------------------------------------------------------
__global__ __launch_bounds__(256)
void cvtk(const float* __restrict__ s, u16* __restrict__ d, int n) {
  const int i = (blockIdx.x * 256 + threadIdx.x) * 4;
  if (i >= n) return;
  const float4 f = *(const float4*)(s + i);
  s16x4 p;
  p[0] = (short)f2bf(f.x); p[1] = (short)f2bf(f.y);
  p[2] = (short)f2bf(f.z); p[3] = (short)f2bf(f.w);
  *(s16x4*)(d + i) = p;
}

// ---------------------------------------------------------------------------
__global__ __launch_bounds__(256)
void lnk(const float* __restrict__ x, const float* __restrict__ gw,
         const float* __restrict__ bw, u16* __restrict__ y,
         u16* __restrict__ xv, int viewmajor) {
  const int lane = threadIdx.x & 63;
  const int tok = blockIdx.x * 4 + (threadIdx.x >> 6);
  const float* xr = x + (size_t)tok * 768;
  float4 v[3];
  float s = 0.f, sq = 0.f;
#pragma unroll
  for (int j = 0; j < 3; ++j) {
    v[j] = *(const float4*)(xr + j * 256 + lane * 4);
    s  += v[j].x + v[j].y + v[j].z + v[j].w;
    sq += v[j].x * v[j].x + v[j].y * v[j].y + v[j].z * v[j].z + v[j].w * v[j].w;
  }
#pragma unroll
  for (int o = 1; o < 64; o <<= 1) { s += __shfl_xor(s, o); sq += __shfl_xor(sq, o); }
  const float mean = s * (1.f / 768.f);
  const float var  = sq * (1.f / 768.f) - mean * mean;
  const float rstd = rsqrtf(var + 1e-5f);
  size_t yrow = (size_t)tok;
  if (viewmajor) {
    const int b_ = tok >> 14, vv = (tok >> 13) & 1, l_ = tok & 8191;
    yrow = ((size_t)((vv << 2) + b_) << 13) + l_;
  }
#pragma unroll
  for (int j = 0; j < 3; ++j) {
    const float4 g4 = *(const float4*)(gw + j * 256 + lane * 4);
    const float4 b4 = *(const float4*)(bw + j * 256 + lane * 4);
    s16x4 py;
    py[0] = (short)f2bf((v[j].x - mean) * rstd * g4.x + b4.x);
    py[1] = (short)f2bf((v[j].y - mean) * rstd * g4.y + b4.y);
    py[2] = (short)f2bf((v[j].z - mean) * rstd * g4.z + b4.z);
    py[3] = (short)f2bf((v[j].w - mean) * rstd * g4.w + b4.w);
    *(s16x4*)(y + yrow * 768 + j * 256 + lane * 4) = py;
    if (xv) {
      s16x4 px;
      px[0] = (short)f2bf(v[j].x); px[1] = (short)f2bf(v[j].y);
      px[2] = (short)f2bf(v[j].z); px[3] = (short)f2bf(v[j].w);
      *(s16x4*)(xv + yrow * 768 + j * 256 + lane * 4) = px;
    }
  }
}

// ---------------------------------------------------------------------------
// Persistent-panel GEMM. grid=256 (1 block/CU): block owns m-tile mt=bid and
// sweeps TN n-tiles as ONE continuous virtual K-loop of KT*TN K-tiles (8-phase
// body unchanged from r7; staging addresses roll across tile boundaries;
// epilogue fires inline every KT tiles, barrier-free, overlapping the
// in-flight next-tile stages). Per-m-half A/B/bias selection fuses the paired
// cross-view GEMMs (M=65536 everywhere).
// MODE 0: C bf16 [row][N]     1: Vt transposed [att][b][h][64][8192]
//      2: out fp32 = x + acc (window un-roll scatter)
//      3: C bf16 = gelu(acc)  4: out fp32 += acc
// ---------------------------------------------------------------------------
template<int MODE, int KT, int TN>
__global__ __launch_bounds__(512, 2)
void gemm_bt(const u16* __restrict__ A1, const u16* __restrict__ A2,
             const u16* __restrict__ B1, const u16* __restrict__ B2,
             const float* __restrict__ bias1, const float* __restrict__ bias2,
             void* __restrict__ Cp, int N, int K,
             const float* __restrict__ xres, const int* __restrict__ idxp) {
  __shared__ char lds[131072];   // A: [2buf][256][128B] @0; B same @65536
  const int t = threadIdx.x;
  const int lane = t & 63;
  const int wid = t >> 6;
  const int wm = wid >> 2, wn = wid & 3;

  // XCD-bijective swizzle for 256 blocks
  const int mt = (blockIdx.x & 7) * 32 + (blockIdx.x >> 3);
  const bool lo = mt < 128;
  const u16* A = lo ? A1 : A2;
  const u16* B = lo ? B1 : B2;
  const float* bias = lo ? bias1 : bias2;

  const int urow = t >> 3;
  const int koff = ((t & 7) ^ (urow & 7)) << 3;  // inverse-swizzled k
  const u16* Asrc = A + (size_t)(mt * 256 + urow) * K + koff;
  const u16* Bsrc = B + (size_t)urow * K + koff;
  const size_t BT = (size_t)256 * K;
  const int wdst = wid << 10;

  auto stgA = [&](int d, int kt, int u0) {
    char* base = (char*)lds + d * 32768 + wdst;
    gld_lds16(Asrc + (size_t)(u0 * 64) * K + kt * 64, base + u0 * 8192);
    gld_lds16(Asrc + (size_t)(u0 * 64 + 64) * K + kt * 64, base + u0 * 8192 + 8192);
  };
  auto stgB = [&](int d, const u16* bs, int kt, int u0) {
    char* base = (char*)lds + 65536 + d * 32768 + wdst;
    gld_lds16(bs + (size_t)(u0 * 64) * K + kt * 64, base + u0 * 8192);
    gld_lds16(bs + (size_t)(u0 * 64 + 64) * K + kt * 64, base + u0 * 8192 + 8192);
  };

  const int c15 = lane & 15, g = lane >> 4;
  const int axor = c15 & 7;
  const char* LAb = (char*)lds + (wm * 128 + c15) * 128;
  const char* LBb = (char*)lds + 65536 + (wn * 64 + c15) * 128;
  bf16x8 av[4][2], bv[4][2];
  auto rdA = [&](int d, int mh) {
#pragma unroll
    for (int m = 0; m < 4; ++m)
#pragma unroll
      for (int ks = 0; ks < 2; ++ks)
        av[m][ks] = *(const bf16x8*)(LAb + d * 32768 + (mh * 64 + m * 16) * 128 +
                                     (((ks << 2) | g) ^ axor) * 16);
  };
  auto rdB = [&](int d) {
#pragma unroll
    for (int n = 0; n < 4; ++n)
#pragma unroll
      for (int ks = 0; ks < 2; ++ks)
        bv[n][ks] = *(const bf16x8*)(LBb + d * 32768 + (n * 16) * 128 +
                                     (((ks << 2) | g) ^ axor) * 16);
  };

  f32x4 acc[8][4] = {};
  auto QD = [&](int mh, int nh) {
    __builtin_amdgcn_s_setprio(1);
#pragma unroll
    for (int ks = 0; ks < 2; ++ks)
#pragma unroll
      for (int m = 0; m < 4; ++m)
#pragma unroll
        for (int n = 0; n < 2; ++n)
          acc[mh * 4 + m][nh * 2 + n] = __builtin_amdgcn_mfma_f32_16x16x32_bf16(
              av[m][ks], bv[nh * 2 + n][ks], acc[mh * 4 + m][nh * 2 + n], 0, 0, 0);
    __builtin_amdgcn_s_setprio(0);
  };

  // barrier-free per-tile epilogue (also resets acc)
  auto epi = [&](int nt) {
    int shift = 0;
    if constexpr (MODE == 2) shift = (idxp[0] & 1) ? 256 : 0;
    const int rb0 = mt * 256 + wm * 128 + (g << 2);
    const int cbase = nt * 256 + wn * 64 + c15;
#pragma unroll
    for (int mi = 0; mi < 8; ++mi) {
      const int row = rb0 + mi * 16;
#pragma unroll
      for (int nj = 0; nj < 4; ++nj) {
        const int col = cbase + nj * 16;
        const float bvv = bias[col];
        if constexpr (MODE == 0) {
          u16* C = (u16*)Cp;
#pragma unroll
          for (int r = 0; r < 4; ++r)
            C[(size_t)(row + r) * N + col] = f2bf(acc[mi][nj][r] + bvv);
        } else if constexpr (MODE == 1) {
          u16* C = (u16*)Cp + (size_t)(row >> 15) * VSZ;
          const int r32 = row & 32767;
          const int hh = col >> 6, dd = col & 63;
          const int b_ = r32 >> 13, l_ = r32 & 8191;
          s16x4 pk;
#pragma unroll
          for (int r = 0; r < 4; ++r) pk[r] = (short)f2bf(acc[mi][nj][r] + bvv);
          *(s16x4*)(C + (((size_t)((b_ * 12 + hh) << 6) + dd) << 13) + l_) = pk;
        } else if constexpr (MODE == 2) {
          float* C = (float*)Cp;
          const int att = row >> 15;
          const int r32 = row & 32767;
          const int b_ = r32 >> 13, p_ = r32 & 8191;
          const int l0 = (p_ - shift) & 8191;
          const size_t rbase = ((size_t)((b_ << 1) + att) << 13) + l0;
#pragma unroll
          for (int r = 0; r < 4; ++r) {
            const size_t idx = (rbase + r) * 768 + col;
            C[idx] = xres[idx] + acc[mi][nj][r] + bvv;
          }
        } else if constexpr (MODE == 3) {
          u16* C = (u16*)Cp;
#pragma unroll
          for (int r = 0; r < 4; ++r) {
            const float u = acc[mi][nj][r] + bvv;
            const float e = __builtin_amdgcn_exp2f(-2.45546693f * u);
            C[(size_t)(row + r) * N + col] = f2bf(u / (1.f + e));
          }
        } else {
          float* C = (float*)Cp;
#pragma unroll
          for (int r = 0; r < 4; ++r) {
            const size_t idx = (size_t)(row + r) * 768 + col;
            C[idx] = C[idx] + acc[mi][nj][r] + bvv;
          }
        }
        acc[mi][nj] = f32x4{0.f, 0.f, 0.f, 0.f};
      }
    }
  };

  constexpr int total = KT * TN;
  constexpr int niter = total >> 1;

  // prologue: vkt 0 full (8 loads), vkt 1 all but A23 (6) — both tile 0
  stgA(0, 0, 0); stgA(0, 0, 2); stgB(0, Bsrc, 0, 0); stgB(0, Bsrc, 0, 2);
  stgB(1, Bsrc, 1, 0); stgB(1, Bsrc, 1, 2); stgA(1, 1, 0);
  asm volatile("s_waitcnt vmcnt(6)" ::: "memory");
  SBAR; SCHED;

#pragma unroll 1
  for (int it = 0; it < niter; ++it) {
    const int i2 = it * 2;
    const int k1 = (i2 + 1) % KT;
    int v2 = i2 + 2; if (v2 > total - 1) v2 = total - 1;
    int v3 = i2 + 3; if (v3 > total - 1) v3 = total - 1;
    const int j2 = v2 / KT, k2 = v2 - j2 * KT;
    const int j3 = v3 / KT, k3 = v3 - j3 * KT;
    const u16* Bs2 = Bsrc + (size_t)j2 * BT;
    const u16* Bs3 = Bsrc + (size_t)j3 * BT;

    // P1
    rdA(0, 0); rdB(0); stgA(1, k1, 2);
    SCHED; SBAR; SCHED; QD(0, 0); SCHED; SBAR; SCHED;
    // P2
    stgB(0, Bs2, k2, 0);
    SCHED; SBAR; SCHED; QD(0, 1); SCHED; SBAR; SCHED;
    // P3
    rdA(0, 1); stgB(0, Bs2, k2, 2);
    SCHED; SBAR; SCHED; QD(1, 1); SCHED; SBAR; SCHED;
    // P4
    stgA(0, k2, 0);
    asm volatile("s_waitcnt vmcnt(6)" ::: "memory");
    SCHED; SBAR; SCHED; QD(1, 0); SCHED; SBAR; SCHED;
    // P5
    rdA(1, 0); rdB(1); stgA(0, k2, 2);
    SCHED; SBAR; SCHED; QD(0, 0); SCHED; SBAR; SCHED;
    // P6
    stgB(1, Bs3, k3, 0);
    SCHED; SBAR; SCHED; QD(0, 1); SCHED; SBAR; SCHED;
    // P7
    rdA(1, 1); stgB(1, Bs3, k3, 2);
    SCHED; SBAR; SCHED; QD(1, 1); SCHED; SBAR; SCHED;
    // P8
    stgA(1, k3, 0);
    asm volatile("s_waitcnt vmcnt(6)" ::: "memory");
    SCHED; SBAR; SCHED; QD(1, 0); SCHED; SBAR; SCHED;

    if (((i2 + 2) % KT) == 0) epi((i2 + 1) / KT);
  }
  asm volatile("s_waitcnt vmcnt(0)" ::: "memory");
}

// ---------------------------------------------------------------------------
// Windowed cross-view attention (unchanged from r3; refcheck-passing).
// ---------------------------------------------------------------------------
__global__ __launch_bounds__(256)
void attnk(const u16* __restrict__ Q1, const u16* __restrict__ K1, const u16* __restrict__ V1,
           const u16* __restrict__ Q2, const u16* __restrict__ K2, const u16* __restrict__ V2,
           u16* __restrict__ O, const int* __restrict__ idxp) {
  const int lane = threadIdx.x & 63;
  const int c = lane & 15, g = lane >> 4;
  const int unit = blockIdx.x * 4 + (threadIdx.x >> 6);
  const int qc = unit & 7;
  int u2 = unit >> 3;
  const int h = u2 % 12; u2 /= 12;
  const int w = u2 & 15; u2 >>= 4;
  const int b = u2 & 3;
  const int a = u2 >> 2;
  const int shift = (idxp[0] & 1) ? 256 : 0;

  const u16* Q  = a ? Q2 : Q1;
  const u16* Kb = a ? K2 : K1;
  const u16* Vt = a ? V2 : V1;

  const int qrow0 = b * 8192 + w * 512 + qc * 64;
  bf16x8 qf[4][2];
#pragma unroll
  for (int q = 0; q < 4; ++q)
#pragma unroll
    for (int hf = 0; hf < 2; ++hf)
      qf[q][hf] = *(const bf16x8*)(Q + (size_t)(qrow0 + q * 16 + c) * 768 + h * 64 + hf * 32 + g * 8);

  f32x4 oacc[4][4] = {};
  f32x4 psum[4] = {};
  const short* Vts = (const short*)Vt + (((size_t)((b * 12 + h) << 6)) << 13);
  const int kbase = b * 8192 + w * 512;
  const float CEXP = 0.125f * L2E;

  for (int kt = 0; kt < 32; ++kt) {
    const size_t krow = (size_t)(kbase + kt * 16 + c) * 768 + h * 64 + g * 8;
    const bf16x8 kf0 = *(const bf16x8*)(Kb + krow);
    const bf16x8 kf1 = *(const bf16x8*)(Kb + krow + 32);
    const int lv = (w * 512 + kt * 16 + g * 4 - shift) & 8191;
    s16x4 vf[4];
#pragma unroll
    for (int df = 0; df < 4; ++df)
      vf[df] = *(const s16x4*)(Vts + ((size_t)(df * 16 + c) << 13) + lv);

    const f32x4 z = {0.f, 0.f, 0.f, 0.f};
    s16x4 pk[4];
#pragma unroll
    for (int q = 0; q < 4; ++q) {
      f32x4 sc2 = __builtin_amdgcn_mfma_f32_16x16x32_bf16(kf0, qf[q][0], z, 0, 0, 0);
      sc2 = __builtin_amdgcn_mfma_f32_16x16x32_bf16(kf1, qf[q][1], sc2, 0, 0, 0);
      f32x4 pv;
      pv[0] = __builtin_amdgcn_exp2f(sc2[0] * CEXP);
      pv[1] = __builtin_amdgcn_exp2f(sc2[1] * CEXP);
      pv[2] = __builtin_amdgcn_exp2f(sc2[2] * CEXP);
      pv[3] = __builtin_amdgcn_exp2f(sc2[3] * CEXP);
      psum[q] += pv;
      pk[q][0] = (short)f2bf(pv[0]);
      pk[q][1] = (short)f2bf(pv[1]);
      pk[q][2] = (short)f2bf(pv[2]);
      pk[q][3] = (short)f2bf(pv[3]);
    }
#pragma unroll
    for (int df = 0; df < 4; ++df)
#pragma unroll
      for (int q = 0; q < 4; ++q)
        oacc[df][q] = __builtin_amdgcn_mfma_f32_16x16x16bf16_1k(vf[df], pk[q], oacc[df][q], 0, 0, 0);
  }

  const size_t orow0 = (size_t)(a * 32768 + qrow0);
#pragma unroll
  for (int q = 0; q < 4; ++q) {
    float ss = psum[q][0] + psum[q][1] + psum[q][2] + psum[q][3];
    ss += __shfl_xor(ss, 16);
    ss += __shfl_xor(ss, 32);
    const float inv = 1.f / ss;
#pragma unroll
    for (int df = 0; df < 4; ++df) {
      s16x4 po;
#pragma unroll
      for (int r = 0; r < 4; ++r) po[r] = (short)f2bf(oacc[df][q][r] * inv);
      *(s16x4*)(O + (orow0 + q * 16 + c) * 768 + h * 64 + df * 16 + g * 4) = po;
    }
  }
}

// ---------------------------------------------------------------------------
extern "C" void kernel_launch(void* const* d_in, const int* in_sizes, int n_in,
                              void* d_out, int out_size, void* d_ws, size_t ws_size,
                              hipStream_t stream) {
  const float* x       = (const float*)d_in[0];
  const float* ln1_g   = (const float*)d_in[1];
  const float* ln1_b   = (const float*)d_in[2];
  const float* ln2_g   = (const float*)d_in[3];
  const float* ln2_b   = (const float*)d_in[4];
  const float* a1_wqkv = (const float*)d_in[5];
  const float* a1_bqkv = (const float*)d_in[6];
  const float* a1_wo   = (const float*)d_in[7];
  const float* a1_bo   = (const float*)d_in[8];
  const float* a2_wqkv = (const float*)d_in[9];
  const float* a2_bqkv = (const float*)d_in[10];
  const float* a2_wo   = (const float*)d_in[11];
  const float* a2_bo   = (const float*)d_in[12];
  const float* fc_w    = (const float*)d_in[13];
  const float* fc_b    = (const float*)d_in[14];
  const float* proj_w  = (const float*)d_in[15];
  const float* proj_b  = (const float*)d_in[16];
  const int*   idxp    = (const int*)d_in[17];
  float* out = (float*)d_out;

  u16* p = (u16*)d_ws;
  u16* w1  = p; p += (size_t)2304 * 768;
  u16* w2  = p; p += (size_t)2304 * 768;
  u16* wo1 = p; p += (size_t)768 * 768;
  u16* wo2 = p; p += (size_t)768 * 768;
  u16* fcw = p; p += (size_t)3072 * 768;
  u16* pjw = p; p += (size_t)768 * 3072;
  u16* y   = p; p += (size_t)65536 * 768;
  u16* xv  = p; p += (size_t)65536 * 768;
  u16* QQ  = p; p += (size_t)65536 * 768;   // [att1 rows | att2 rows]
  u16* KK  = p; p += (size_t)65536 * 768;
  u16* VV  = p; p += (size_t)65536 * 768;   // [att][b][h][64][8192]
  u16* Ob  = p; p += (size_t)65536 * 768;
  u16* hb  = QQ;  // MLP hidden [65536][3072] aliases QQ..Ob (exactly fits)

  cvtk<<<1728, 256, 0, stream>>>(a1_wqkv, w1, 2304 * 768);
  cvtk<<<1728, 256, 0, stream>>>(a2_wqkv, w2, 2304 * 768);
  cvtk<<<576,  256, 0, stream>>>(a1_wo, wo1, 768 * 768);
  cvtk<<<576,  256, 0, stream>>>(a2_wo, wo2, 768 * 768);
  cvtk<<<2304, 256, 0, stream>>>(fc_w, fcw, 3072 * 768);
  cvtk<<<2304, 256, 0, stream>>>(proj_w, pjw, 768 * 3072);

  lnk<<<16384, 256, 0, stream>>>(x, ln1_g, ln1_b, y, xv, 1);

  const size_t VS = (size_t)VSZ;
  // Q: [Q1;Q2] = [y0@w1q ; y1@w2q]  (A = y globally)
  gemm_bt<0, 12, 3><<<256, 512, 0, stream>>>(y, y, w1, w2, a1_bqkv, a2_bqkv,
                                             QQ, 768, 768, nullptr, idxp);
  // K: [K1;K2] = [y1@w1k ; y0@w2k]  (A1 = y+VS; A2 = y-VS, only deref'd >= y)
  gemm_bt<0, 12, 3><<<256, 512, 0, stream>>>(y + VS, y - VS, w1 + 768 * 768, w2 + 768 * 768,
                                             a1_bqkv + 768, a2_bqkv + 768,
                                             KK, 768, 768, nullptr, idxp);
  // V: [V1;V2] = [xv0@w1v ; xv1@w2v] transposed per-head
  gemm_bt<1, 12, 3><<<256, 512, 0, stream>>>(xv, xv, w1 + 2 * 768 * 768, w2 + 2 * 768 * 768,
                                             a1_bqkv + 1536, a2_bqkv + 1536,
                                             VV, 768, 768, nullptr, idxp);

  attnk<<<3072, 256, 0, stream>>>(QQ, KK, VV, QQ + VS, KK + VS, VV + VS, Ob, idxp);

  // out-proj + residual -> d_out (both attns in one dispatch)
  gemm_bt<2, 12, 3><<<256, 512, 0, stream>>>(Ob, Ob, wo1, wo2, a1_bo, a2_bo,
                                             out, 768, 768, x, idxp);

  lnk<<<16384, 256, 0, stream>>>(out, ln2_g, ln2_b, y, nullptr, 0);

  // FC + GELU
  gemm_bt<3, 12, 12><<<256, 512, 0, stream>>>(y, y, fcw, fcw, fc_b, fc_b,
                                              hb, 3072, 768, nullptr, idxp);
  // proj + residual
  gemm_bt<4, 48, 3><<<256, 512, 0, stream>>>(hb, hb, pjw, pjw, proj_b, proj_b,
                                             out, 768, 3072, nullptr, idxp);
}

// Round 9
// 1502.447 us; speedup vs baseline: 1.2092x; 1.2092x over previous
//
#include <hip/hip_runtime.h>
#include <hip/hip_bf16.h>

typedef __bf16 bf16x8 __attribute__((ext_vector_type(8)));
typedef float  f32x4  __attribute__((ext_vector_type(4)));
typedef short  s16x4  __attribute__((ext_vector_type(4)));
typedef unsigned short u16;

#define L2E 1.44269504088896f
#define SBAR  __builtin_amdgcn_s_barrier()
#define SCHED __builtin_amdgcn_sched_barrier(0)

static __device__ __forceinline__ u16 f2bf(float f) {
  unsigned u = __builtin_bit_cast(unsigned, f);
  u += 0x7fffu + ((u >> 16) & 1u);
  return (u16)(u >> 16);
}

static __device__ __forceinline__ void gld_lds16(const void* g, void* l) {
  __builtin_amdgcn_global_load_lds((const __attribute__((address_space(1))) unsigned*)g,
                                   (__attribute__((address_space(3))) unsigned*)l, 16, 0, 0);
}

// ---------------------------------------------------------------------------
__global__ __launch_bounds__(256)
void cvtk(const float* __restrict__ s, u16* __restrict__ d, int n) {
  const int i = (blockIdx.x * 256 + threadIdx.x) * 4;
  if (i >= n) return;
  const float4 f = *(const float4*)(s + i);
  s16x4 p;
  p[0] = (short)f2bf(f.x); p[1] = (short)f2bf(f.y);
  p[2] = (short)f2bf(f.z); p[3] = (short)f2bf(f.w);
  *(s16x4*)(d + i) = p;
}

// ---------------------------------------------------------------------------
__global__ __launch_bounds__(256)
void lnk(const float* __restrict__ x, const float* __restrict__ gw,
         const float* __restrict__ bw, u16* __restrict__ y,
         u16* __restrict__ xv, int viewmajor) {
  const int lane = threadIdx.x & 63;
  const int tok = blockIdx.x * 4 + (threadIdx.x >> 6);
  const float* xr = x + (size_t)tok * 768;
  float4 v[3];
  float s = 0.f, sq = 0.f;
#pragma unroll
  for (int j = 0; j < 3; ++j) {
    v[j] = *(const float4*)(xr + j * 256 + lane * 4);
    s  += v[j].x + v[j].y + v[j].z + v[j].w;
    sq += v[j].x * v[j].x + v[j].y * v[j].y + v[j].z * v[j].z + v[j].w * v[j].w;
  }
#pragma unroll
  for (int o = 1; o < 64; o <<= 1) { s += __shfl_xor(s, o); sq += __shfl_xor(sq, o); }
  const float mean = s * (1.f / 768.f);
  const float var  = sq * (1.f / 768.f) - mean * mean;
  const float rstd = rsqrtf(var + 1e-5f);
  size_t yrow = (size_t)tok;
  if (viewmajor) {
    const int b_ = tok >> 14, vv = (tok >> 13) & 1, l_ = tok & 8191;
    yrow = ((size_t)((vv << 2) + b_) << 13) + l_;
  }
#pragma unroll
  for (int j = 0; j < 3; ++j) {
    const float4 g4 = *(const float4*)(gw + j * 256 + lane * 4);
    const float4 b4 = *(const float4*)(bw + j * 256 + lane * 4);
    s16x4 py;
    py[0] = (short)f2bf((v[j].x - mean) * rstd * g4.x + b4.x);
    py[1] = (short)f2bf((v[j].y - mean) * rstd * g4.y + b4.y);
    py[2] = (short)f2bf((v[j].z - mean) * rstd * g4.z + b4.z);
    py[3] = (short)f2bf((v[j].w - mean) * rstd * g4.w + b4.w);
    *(s16x4*)(y + yrow * 768 + j * 256 + lane * 4) = py;
    if (xv) {
      s16x4 px;
      px[0] = (short)f2bf(v[j].x); px[1] = (short)f2bf(v[j].y);
      px[2] = (short)f2bf(v[j].z); px[3] = (short)f2bf(v[j].w);
      *(s16x4*)(xv + yrow * 768 + j * 256 + lane * 4) = px;
    }
  }
}

// ---------------------------------------------------------------------------
// GEMM (round-7 structure, best measured): 8-phase, BM=BN=256, BK=64, 8 waves,
// 2 K-tiles/iter, vmcnt(6) at phases 4/8 only, XOR-swizzled LDS.
// ---------------------------------------------------------------------------
template<int MODE>
__global__ __launch_bounds__(512, 2)
void gemm_bt(const u16* __restrict__ A, const u16* __restrict__ B,
             const float* __restrict__ bias, void* __restrict__ Cp,
             int N, int K,
             const float* __restrict__ xres, const int* __restrict__ idxp,
             int vview) {
  __shared__ char lds[131072];
  const int t = threadIdx.x;
  const int lane = t & 63;
  const int wid = t >> 6;
  const int wm = wid >> 2, wn = wid & 3;

  const int cpx = gridDim.x >> 3;
  const int bid = (blockIdx.x & 7) * cpx + (blockIdx.x >> 3);
  const int Ntiles = N >> 8;
  const int PPB = Ntiles << 3;
  const int panel = bid / PPB;
  const int rem = bid - panel * PPB;
  const int nt = rem >> 3;
  const int mt = (panel << 3) + (rem & 7);

  const int urow = t >> 3;
  const int koff = ((t & 7) ^ (urow & 7)) << 3;
  const u16* Asrc = A + (size_t)(mt * 256 + urow) * K + koff;
  const u16* Bsrc = B + (size_t)(nt * 256 + urow) * K + koff;
  const int wdst = wid << 10;

  auto stgA = [&](int d, int kt, int u0) {
    char* base = (char*)lds + d * 32768 + wdst;
    gld_lds16(Asrc + (size_t)(u0 * 64) * K + kt * 64, base + u0 * 8192);
    gld_lds16(Asrc + (size_t)(u0 * 64 + 64) * K + kt * 64, base + u0 * 8192 + 8192);
  };
  auto stgB = [&](int d, int kt, int u0) {
    char* base = (char*)lds + 65536 + d * 32768 + wdst;
    gld_lds16(Bsrc + (size_t)(u0 * 64) * K + kt * 64, base + u0 * 8192);
    gld_lds16(Bsrc + (size_t)(u0 * 64 + 64) * K + kt * 64, base + u0 * 8192 + 8192);
  };

  const int c15 = lane & 15, g = lane >> 4;
  const int axor = c15 & 7;
  const char* LAb = (char*)lds + (wm * 128 + c15) * 128;
  const char* LBb = (char*)lds + 65536 + (wn * 64 + c15) * 128;
  bf16x8 av[4][2], bv[4][2];
  auto rdA = [&](int d, int mh) {
#pragma unroll
    for (int m = 0; m < 4; ++m)
#pragma unroll
      for (int ks = 0; ks < 2; ++ks)
        av[m][ks] = *(const bf16x8*)(LAb + d * 32768 + (mh * 64 + m * 16) * 128 +
                                     (((ks << 2) | g) ^ axor) * 16);
  };
  auto rdB = [&](int d) {
#pragma unroll
    for (int n = 0; n < 4; ++n)
#pragma unroll
      for (int ks = 0; ks < 2; ++ks)
        bv[n][ks] = *(const bf16x8*)(LBb + d * 32768 + (n * 16) * 128 +
                                     (((ks << 2) | g) ^ axor) * 16);
  };

  f32x4 acc[8][4] = {};
  auto QD = [&](int mh, int nh) {
    __builtin_amdgcn_s_setprio(1);
#pragma unroll
    for (int ks = 0; ks < 2; ++ks)
#pragma unroll
      for (int m = 0; m < 4; ++m)
#pragma unroll
        for (int n = 0; n < 2; ++n)
          acc[mh * 4 + m][nh * 2 + n] = __builtin_amdgcn_mfma_f32_16x16x32_bf16(
              av[m][ks], bv[nh * 2 + n][ks], acc[mh * 4 + m][nh * 2 + n], 0, 0, 0);
    __builtin_amdgcn_s_setprio(0);
  };

  const int nk = K >> 6, niter = nk >> 1, last = nk - 1;

  stgA(0, 0, 0); stgA(0, 0, 2); stgB(0, 0, 0); stgB(0, 0, 2);
  stgB(1, 1, 0); stgB(1, 1, 2); stgA(1, 1, 0);
  asm volatile("s_waitcnt vmcnt(6)" ::: "memory");
  SBAR; SCHED;

  for (int it = 0; it < niter; ++it) {
    const int i2 = it * 2;
    const int t1 = (i2 + 1 < nk) ? i2 + 1 : last;
    const int t2 = (i2 + 2 < nk) ? i2 + 2 : last;
    const int t3 = (i2 + 3 < nk) ? i2 + 3 : last;

    rdA(0, 0); rdB(0); stgA(1, t1, 2);
    SCHED; SBAR; SCHED; QD(0, 0); SCHED; SBAR; SCHED;
    stgB(0, t2, 0);
    SCHED; SBAR; SCHED; QD(0, 1); SCHED; SBAR; SCHED;
    rdA(0, 1); stgB(0, t2, 2);
    SCHED; SBAR; SCHED; QD(1, 1); SCHED; SBAR; SCHED;
    stgA(0, t2, 0);
    asm volatile("s_waitcnt vmcnt(6)" ::: "memory");
    SCHED; SBAR; SCHED; QD(1, 0); SCHED; SBAR; SCHED;
    rdA(1, 0); rdB(1); stgA(0, t2, 2);
    SCHED; SBAR; SCHED; QD(0, 0); SCHED; SBAR; SCHED;
    stgB(1, t3, 0);
    SCHED; SBAR; SCHED; QD(0, 1); SCHED; SBAR; SCHED;
    rdA(1, 1); stgB(1, t3, 2);
    SCHED; SBAR; SCHED; QD(1, 1); SCHED; SBAR; SCHED;
    stgA(1, t3, 0);
    asm volatile("s_waitcnt vmcnt(6)" ::: "memory");
    SCHED; SBAR; SCHED; QD(1, 0); SCHED; SBAR; SCHED;
  }

  int shift = 0;
  if constexpr (MODE == 2) shift = (idxp[0] & 1) ? 256 : 0;

  const int rb0 = mt * 256 + wm * 128 + (g << 2);
  const int cbase = nt * 256 + wn * 64 + c15;
#pragma unroll
  for (int mi = 0; mi < 8; ++mi) {
    const int row = rb0 + mi * 16;
#pragma unroll
    for (int nj = 0; nj < 4; ++nj) {
      const int col = cbase + nj * 16;
      const float bvv = bias[col];
      if constexpr (MODE == 0) {
        u16* C = (u16*)Cp;
#pragma unroll
        for (int r = 0; r < 4; ++r)
          C[(size_t)(row + r) * N + col] = f2bf(acc[mi][nj][r] + bvv);
      } else if constexpr (MODE == 1) {
        u16* C = (u16*)Cp;
        const int hh = col >> 6, dd = col & 63;
        const int b_ = row >> 13, l_ = row & 8191;
        s16x4 pk;
#pragma unroll
        for (int r = 0; r < 4; ++r) pk[r] = (short)f2bf(acc[mi][nj][r] + bvv);
        *(s16x4*)(C + (((size_t)((b_ * 12 + hh) << 6) + dd) << 13) + l_) = pk;
      } else if constexpr (MODE == 2) {
        float* C = (float*)Cp;
        const int b_ = row >> 13, p_ = row & 8191;
        const int l0 = (p_ - shift) & 8191;
        const size_t rbase = ((size_t)((b_ << 1) + vview) << 13) + l0;
#pragma unroll
        for (int r = 0; r < 4; ++r) {
          const size_t idx = (rbase + r) * 768 + col;
          C[idx] = xres[idx] + acc[mi][nj][r] + bvv;
        }
      } else if constexpr (MODE == 3) {
        u16* C = (u16*)Cp;
#pragma unroll
        for (int r = 0; r < 4; ++r) {
          const float u = acc[mi][nj][r] + bvv;
          const float e = __builtin_amdgcn_exp2f(-2.45546693f * u);
          C[(size_t)(row + r) * N + col] = f2bf(u / (1.f + e));
        }
      } else {
        float* C = (float*)Cp;
#pragma unroll
        for (int r = 0; r < 4; ++r) {
          const size_t idx = (size_t)(row + r) * 768 + col;
          C[idx] = C[idx] + acc[mi][nj][r] + bvv;
        }
      }
    }
  }
}

// ---------------------------------------------------------------------------
// Windowed cross-view attention, LDS-staged K/V.
// Block = one (att,b,win,head), 8 waves = all 512 queries (wave wid owns 64).
// Stage once: K tile [512][64] (XOR-swizzled 16B chunks; same proven pattern
// as GEMM rdA) and V^T tile [64][512] (shift folded in at staging; 16B-chunk
// swizzle). Then 32-kt loop: 2 ds_read_b128 (K) + 4 ds_read_b64 (V) + 8 QK
// MFMA + 16 PV MFMA per wave per kt. No-max softmax (scores bounded;
// shift-invariant). PV mfma_16x16x16bf16_1k B-layout = S^T C-layout.
// ---------------------------------------------------------------------------
__global__ __launch_bounds__(512, 2)
void attnk(const u16* __restrict__ Q1, const u16* __restrict__ K1, const u16* __restrict__ V1,
           const u16* __restrict__ Q2, const u16* __restrict__ K2, const u16* __restrict__ V2,
           u16* __restrict__ O, const int* __restrict__ idxp) {
  __shared__ char lds[131072];   // K @0 (64 KB), V^T @65536 (64 KB)
  const int t = threadIdx.x;
  const int lane = t & 63;
  const int c = lane & 15, g = lane >> 4;
  const int wid = t >> 6;        // q-chunk 0..7
  int bb = blockIdx.x;
  const int h = bb % 12; bb /= 12;
  const int w = bb & 15; bb >>= 4;
  const int b = bb & 3;
  const int a = bb >> 2;
  const int shift = (idxp[0] & 1) ? 256 : 0;

  const u16* Q  = a ? Q2 : Q1;
  const u16* Kb = a ? K2 : K1;
  const u16* Vt = a ? V2 : V1;
  const int kbase = b * 8192 + w * 512;
  const u16* Vts = Vt + ((size_t)(b * 12 + h) << 19);  // [64][8192]

  // Q fragments (global, before staging barrier)
  const int qrow0 = b * 8192 + w * 512 + wid * 64;
  bf16x8 qf[4][2];
#pragma unroll
  for (int q = 0; q < 4; ++q)
#pragma unroll
    for (int hf = 0; hf < 2; ++hf)
      qf[q][hf] = *(const bf16x8*)(Q + (size_t)(qrow0 + q * 16 + c) * 768 + h * 64 + hf * 32 + g * 8);

  // stage K: pass p covers rows p*64+(t>>3), chunk t&7 (16B); swizzled source
  {
    const int r0 = t >> 3, ch = t & 7;
    char* kdst = (char*)lds + (wid << 10);
#pragma unroll
    for (int p = 0; p < 8; ++p) {
      const int row = p * 64 + r0;
      gld_lds16(Kb + (size_t)(kbase + row) * 768 + h * 64 + ((ch ^ (row & 7)) << 3),
                kdst + p * 8192);
    }
    // stage V^T: pass p covers row p*8+wid, chunk16 = lane; shift folded
    char* vdst = (char*)lds + 65536 + (wid << 10);
#pragma unroll
    for (int p = 0; p < 8; ++p) {
      const int vrow = p * 8 + wid;
      const int cg = lane ^ (vrow & 7);
      const int l = (w * 512 + cg * 8 - shift) & 8191;
      gld_lds16(Vts + (size_t)vrow * 8192 + l, vdst + p * 8192);
    }
  }
  __syncthreads();

  f32x4 oacc[4][4] = {};   // [df][q]
  f32x4 psum[4] = {};
  const float CEXP = 0.125f * L2E;
  const char* LK = (char*)lds;
  const char* LV = (char*)lds + 65536;

  for (int kt = 0; kt < 32; ++kt) {
    const int krow = kt * 16 + c;
    const int ksw = krow & 7;
    const bf16x8 kf0 = *(const bf16x8*)(LK + krow * 128 + ((g ^ ksw) << 4));
    const bf16x8 kf1 = *(const bf16x8*)(LK + krow * 128 + (((4 | g) ^ ksw) << 4));
    s16x4 vf[4];
#pragma unroll
    for (int df = 0; df < 4; ++df) {
      const int vr = df * 16 + c;
      vf[df] = *(const s16x4*)(LV + vr * 1024 +
                               (((kt * 2 + (g >> 1)) ^ (vr & 7)) << 4) + ((g & 1) << 3));
    }

    const f32x4 z = {0.f, 0.f, 0.f, 0.f};
    s16x4 pk[4];
#pragma unroll
    for (int q = 0; q < 4; ++q) {
      f32x4 sc2 = __builtin_amdgcn_mfma_f32_16x16x32_bf16(kf0, qf[q][0], z, 0, 0, 0);
      sc2 = __builtin_amdgcn_mfma_f32_16x16x32_bf16(kf1, qf[q][1], sc2, 0, 0, 0);
      f32x4 pv;
      pv[0] = __builtin_amdgcn_exp2f(sc2[0] * CEXP);
      pv[1] = __builtin_amdgcn_exp2f(sc2[1] * CEXP);
      pv[2] = __builtin_amdgcn_exp2f(sc2[2] * CEXP);
      pv[3] = __builtin_amdgcn_exp2f(sc2[3] * CEXP);
      psum[q] += pv;
      pk[q][0] = (short)f2bf(pv[0]);
      pk[q][1] = (short)f2bf(pv[1]);
      pk[q][2] = (short)f2bf(pv[2]);
      pk[q][3] = (short)f2bf(pv[3]);
    }
#pragma unroll
    for (int df = 0; df < 4; ++df)
#pragma unroll
      for (int q = 0; q < 4; ++q)
        oacc[df][q] = __builtin_amdgcn_mfma_f32_16x16x16bf16_1k(vf[df], pk[q], oacc[df][q], 0, 0, 0);
  }

  const size_t orow0 = (size_t)(a * 32768 + qrow0);
#pragma unroll
  for (int q = 0; q < 4; ++q) {
    float ss = psum[q][0] + psum[q][1] + psum[q][2] + psum[q][3];
    ss += __shfl_xor(ss, 16);
    ss += __shfl_xor(ss, 32);
    const float inv = 1.f / ss;
#pragma unroll
    for (int df = 0; df < 4; ++df) {
      s16x4 po;
#pragma unroll
      for (int r = 0; r < 4; ++r) po[r] = (short)f2bf(oacc[df][q][r] * inv);
      *(s16x4*)(O + (orow0 + q * 16 + c) * 768 + h * 64 + df * 16 + g * 4) = po;
    }
  }
}

// ---------------------------------------------------------------------------
extern "C" void kernel_launch(void* const* d_in, const int* in_sizes, int n_in,
                              void* d_out, int out_size, void* d_ws, size_t ws_size,
                              hipStream_t stream) {
  const float* x       = (const float*)d_in[0];
  const float* ln1_g   = (const float*)d_in[1];
  const float* ln1_b   = (const float*)d_in[2];
  const float* ln2_g   = (const float*)d_in[3];
  const float* ln2_b   = (const float*)d_in[4];
  const float* a1_wqkv = (const float*)d_in[5];
  const float* a1_bqkv = (const float*)d_in[6];
  const float* a1_wo   = (const float*)d_in[7];
  const float* a1_bo   = (const float*)d_in[8];
  const float* a2_wqkv = (const float*)d_in[9];
  const float* a2_bqkv = (const float*)d_in[10];
  const float* a2_wo   = (const float*)d_in[11];
  const float* a2_bo   = (const float*)d_in[12];
  const float* fc_w    = (const float*)d_in[13];
  const float* fc_b    = (const float*)d_in[14];
  const float* proj_w  = (const float*)d_in[15];
  const float* proj_b  = (const float*)d_in[16];
  const int*   idxp    = (const int*)d_in[17];
  float* out = (float*)d_out;

  u16* p = (u16*)d_ws;
  u16* w1  = p; p += (size_t)2304 * 768;
  u16* w2  = p; p += (size_t)2304 * 768;
  u16* wo1 = p; p += (size_t)768 * 768;
  u16* wo2 = p; p += (size_t)768 * 768;
  u16* fcw = p; p += (size_t)3072 * 768;
  u16* pjw = p; p += (size_t)768 * 3072;
  u16* y   = p; p += (size_t)65536 * 768;
  u16* xv  = p; p += (size_t)65536 * 768;
  u16* Q1  = p; p += (size_t)32768 * 768;
  u16* K1  = p; p += (size_t)32768 * 768;
  u16* V1  = p; p += (size_t)32768 * 768;
  u16* Q2  = p; p += (size_t)32768 * 768;
  u16* K2  = p; p += (size_t)32768 * 768;
  u16* V2  = p; p += (size_t)32768 * 768;
  u16* Ob  = p; p += (size_t)65536 * 768;
  u16* hb  = Q1;  // MLP hidden aliases Q1..Ob

  cvtk<<<1728, 256, 0, stream>>>(a1_wqkv, w1, 2304 * 768);
  cvtk<<<1728, 256, 0, stream>>>(a2_wqkv, w2, 2304 * 768);
  cvtk<<<576,  256, 0, stream>>>(a1_wo, wo1, 768 * 768);
  cvtk<<<576,  256, 0, stream>>>(a2_wo, wo2, 768 * 768);
  cvtk<<<2304, 256, 0, stream>>>(fc_w, fcw, 3072 * 768);
  cvtk<<<2304, 256, 0, stream>>>(proj_w, pjw, 768 * 3072);

  lnk<<<16384, 256, 0, stream>>>(x, ln1_g, ln1_b, y, xv, 1);

  const size_t VS = (size_t)32768 * 768;
  gemm_bt<0><<<384, 512, 0, stream>>>(y,        w1,                  a1_bqkv,        Q1, 768, 768, nullptr, nullptr, 0);
  gemm_bt<0><<<384, 512, 0, stream>>>(y + VS,   w1 + 768 * 768,      a1_bqkv + 768,  K1, 768, 768, nullptr, nullptr, 0);
  gemm_bt<1><<<384, 512, 0, stream>>>(xv,       w1 + 2 * 768 * 768,  a1_bqkv + 1536, V1, 768, 768, nullptr, nullptr, 0);
  gemm_bt<0><<<384, 512, 0, stream>>>(y + VS,   w2,                  a2_bqkv,        Q2, 768, 768, nullptr, nullptr, 0);
  gemm_bt<0><<<384, 512, 0, stream>>>(y,        w2 + 768 * 768,      a2_bqkv + 768,  K2, 768, 768, nullptr, nullptr, 0);
  gemm_bt<1><<<384, 512, 0, stream>>>(xv + VS,  w2 + 2 * 768 * 768,  a2_bqkv + 1536, V2, 768, 768, nullptr, nullptr, 0);

  // attention: 2*4*16*12 = 1536 blocks x 512 threads (8 waves = 512 queries)
  attnk<<<1536, 512, 0, stream>>>(Q1, K1, V1, Q2, K2, V2, Ob, idxp);

  gemm_bt<2><<<384, 512, 0, stream>>>(Ob,      wo1, a1_bo, out, 768, 768, x, idxp, 0);
  gemm_bt<2><<<384, 512, 0, stream>>>(Ob + VS, wo2, a2_bo, out, 768, 768, x, idxp, 1);

  lnk<<<16384, 256, 0, stream>>>(out, ln2_g, ln2_b, y, nullptr, 0);

  gemm_bt<3><<<3072, 512, 0, stream>>>(y, fcw, fc_b, hb, 3072, 768, nullptr, nullptr, 0);

  gemm_bt<4><<<768, 512, 0, stream>>>(hb, pjw, proj_b, out, 768, 3072, nullptr, nullptr, 0);
}